// Round 1
// baseline (2801.619 us; speedup 1.0000x reference)
//
#include <hip/hip_runtime.h>
#include <hip/hip_bf16.h>

// GPT forward, B=2 T=1024 C=1024 L=4 H=16 HD=64 V=50257.
// Round 0: correctness-first bf16-MFMA implementation.
//   - fp32 residual stream x in ws; activations bf16 at GEMM inputs
//   - GEMM: 16x16x32 bf16 MFMA, wave=32x32 (2x2 frags), WG=64x64, direct
//     global->frag loads (no LDS staging yet; optimize later rounds)
//   - attention: flash-style online softmax, full (UNMASKED) attention per
//     reference; P routed through LDS to A-operand layout; V pre-transposed
//   - LM head: fp32 dot rows of wte vs lnf(x[:, -1]) -- memory bound

constexpr int NB = 2;
constexpr int NT = 1024;
constexpr int NC = 1024;
constexpr int NLAYER = 4;
constexpr int NH = 16;
constexpr int DH = 64;
constexpr int NV = 50257;
constexpr int C3 = 3 * NC;
constexpr int C4 = 4 * NC;

typedef __attribute__((ext_vector_type(8))) short bf16x8;
typedef __attribute__((ext_vector_type(4))) float f32x4;
typedef __attribute__((ext_vector_type(4))) short s16x4;

__device__ inline short f2b(float x) {
  union { __hip_bfloat16 h; short s; } u;
  u.h = __float2bfloat16(x);
  return u.s;
}

__device__ inline bf16x8 cvt8(float4 a, float4 b) {
  bf16x8 r;
  r[0] = f2b(a.x); r[1] = f2b(a.y); r[2] = f2b(a.z); r[3] = f2b(a.w);
  r[4] = f2b(b.x); r[5] = f2b(b.y); r[6] = f2b(b.z); r[7] = f2b(b.w);
  return r;
}

// ---------------- embedding: x[b,t,:] = wte[idx[b,t],:] + wpe[t,:] ---------
__global__ void embed_kernel(const int* __restrict__ idx,
                             const float* __restrict__ wte,
                             const float* __restrict__ wpe,
                             float* __restrict__ x) {
  int row = blockIdx.x;            // 0..NB*NT-1
  int t = row & (NT - 1);
  int id = idx[row];
  const float4* wr = reinterpret_cast<const float4*>(wte + (size_t)id * NC);
  const float4* pr = reinterpret_cast<const float4*>(wpe + (size_t)t * NC);
  float4* xr = reinterpret_cast<float4*>(x + (size_t)row * NC);
  int i = threadIdx.x;             // 256 threads, NC/4 = 256 float4
  float4 a = wr[i], b = pr[i];
  xr[i] = make_float4(a.x + b.x, a.y + b.y, a.z + b.z, a.w + b.w);
}

// ---------------- layernorm: wave per row, out bf16 ------------------------
__global__ __launch_bounds__(256) void ln_kernel(const float* __restrict__ x,
                                                 const float* __restrict__ w,
                                                 const float* __restrict__ bb,
                                                 short* __restrict__ out) {
  int wave = threadIdx.x >> 6;
  int lane = threadIdx.x & 63;
  int row = blockIdx.x * 4 + wave;        // grid=512 -> 2048 rows
  const float4* xr = reinterpret_cast<const float4*>(x + (size_t)row * NC);
  float4 v[4];
  float s = 0.f;
#pragma unroll
  for (int i = 0; i < 4; i++) {
    v[i] = xr[lane + i * 64];
    s += v[i].x + v[i].y + v[i].z + v[i].w;
  }
#pragma unroll
  for (int m = 32; m; m >>= 1) s += __shfl_xor(s, m);
  float mean = s * (1.f / NC);
  float vs = 0.f;
#pragma unroll
  for (int i = 0; i < 4; i++) {
    float a = v[i].x - mean, b = v[i].y - mean, c = v[i].z - mean, d = v[i].w - mean;
    vs += a * a + b * b + c * c + d * d;
  }
#pragma unroll
  for (int m = 32; m; m >>= 1) vs += __shfl_xor(vs, m);
  float rstd = rsqrtf(vs * (1.f / NC) + 1e-5f);
  const float4* wr = reinterpret_cast<const float4*>(w);
  const float4* br = reinterpret_cast<const float4*>(bb);
  s16x4* orow = reinterpret_cast<s16x4*>(out + (size_t)row * NC);
#pragma unroll
  for (int i = 0; i < 4; i++) {
    int ci = lane + i * 64;
    float4 wv = wr[ci], bv = br[ci];
    s16x4 o;
    o[0] = f2b((v[i].x - mean) * rstd * wv.x + bv.x);
    o[1] = f2b((v[i].y - mean) * rstd * wv.y + bv.y);
    o[2] = f2b((v[i].z - mean) * rstd * wv.z + bv.z);
    o[3] = f2b((v[i].w - mean) * rstd * wv.w + bv.w);
    orow[ci] = o;
  }
}

// ---------------- final LN of x[b, NT-1, :] -> xf (fp32) -------------------
__global__ void lnf_kernel(const float* __restrict__ x,
                           const float* __restrict__ w,
                           const float* __restrict__ bb,
                           float* __restrict__ xf) {
  int wave = threadIdx.x >> 6;            // batch index, block=128
  int lane = threadIdx.x & 63;
  size_t row = (size_t)wave * NT + (NT - 1);
  const float4* xr = reinterpret_cast<const float4*>(x + row * NC);
  float4 v[4];
  float s = 0.f;
#pragma unroll
  for (int i = 0; i < 4; i++) {
    v[i] = xr[lane + i * 64];
    s += v[i].x + v[i].y + v[i].z + v[i].w;
  }
#pragma unroll
  for (int m = 32; m; m >>= 1) s += __shfl_xor(s, m);
  float mean = s * (1.f / NC);
  float vs = 0.f;
#pragma unroll
  for (int i = 0; i < 4; i++) {
    float a = v[i].x - mean, b = v[i].y - mean, c = v[i].z - mean, d = v[i].w - mean;
    vs += a * a + b * b + c * c + d * d;
  }
#pragma unroll
  for (int m = 32; m; m >>= 1) vs += __shfl_xor(vs, m);
  float rstd = rsqrtf(vs * (1.f / NC) + 1e-5f);
  const float4* wr = reinterpret_cast<const float4*>(w);
  const float4* br = reinterpret_cast<const float4*>(bb);
  float4* orow = reinterpret_cast<float4*>(xf + (size_t)wave * NC);
#pragma unroll
  for (int i = 0; i < 4; i++) {
    int ci = lane + i * 64;
    float4 wv = wr[ci], bv = br[ci];
    float4 o;
    o.x = (v[i].x - mean) * rstd * wv.x + bv.x;
    o.y = (v[i].y - mean) * rstd * wv.y + bv.y;
    o.z = (v[i].z - mean) * rstd * wv.z + bv.z;
    o.w = (v[i].w - mean) * rstd * wv.w + bv.w;
    orow[ci] = o;
  }
}

// ---------------- GEMM: out = A(bf16,[M=2048 x K]) @ W(f32,[N x K])^T + b --
// EPI: 0 = store bf16, 1 = residual add into f32 buffer, 2 = GELU -> bf16
template <int EPI>
__global__ __launch_bounds__(256) void gemm_kernel(
    const short* __restrict__ A, const float* __restrict__ W,
    const float* __restrict__ bias, float* __restrict__ outF,
    short* __restrict__ outB, int N, int K) {
  int lane = threadIdx.x & 63;
  int wave = threadIdx.x >> 6;
  int quad = lane >> 4, l16 = lane & 15;
  int m_base = blockIdx.y * 64 + (wave >> 1) * 32;
  int n_base = blockIdx.x * 64 + (wave & 1) * 32;
  f32x4 acc[2][2] = {};
  for (int k0 = 0; k0 < K; k0 += 32) {
    bf16x8 a[2], b[2];
#pragma unroll
    for (int i = 0; i < 2; i++) {
      const short* ap = A + (size_t)(m_base + i * 16 + l16) * K + k0 + quad * 8;
      a[i] = *reinterpret_cast<const bf16x8*>(ap);
    }
#pragma unroll
    for (int j = 0; j < 2; j++) {
      const float* wp = W + (size_t)(n_base + j * 16 + l16) * K + k0 + quad * 8;
      float4 w0 = reinterpret_cast<const float4*>(wp)[0];
      float4 w1 = reinterpret_cast<const float4*>(wp)[1];
      b[j] = cvt8(w0, w1);
    }
#pragma unroll
    for (int i = 0; i < 2; i++)
#pragma unroll
      for (int j = 0; j < 2; j++)
        acc[i][j] = __builtin_amdgcn_mfma_f32_16x16x32_bf16(a[i], b[j], acc[i][j], 0, 0, 0);
  }
#pragma unroll
  for (int i = 0; i < 2; i++)
#pragma unroll
    for (int j = 0; j < 2; j++) {
      int col = n_base + j * 16 + l16;
      float bv = bias[col];
#pragma unroll
      for (int r = 0; r < 4; r++) {
        int row = m_base + i * 16 + quad * 4 + r;
        float vv = acc[i][j][r] + bv;
        size_t off = (size_t)row * N + col;
        if constexpr (EPI == 0) {
          outB[off] = f2b(vv);
        } else if constexpr (EPI == 1) {
          outF[off] += vv;
        } else {
          float g = 0.5f * vv * (1.f + erff(vv * 0.70710678f));
          outB[off] = f2b(g);
        }
      }
    }
}

// ---------------- V transpose: qkv v-part -> vT[bh, d, t] bf16 -------------
__global__ void vrepack_kernel(const short* __restrict__ qkv,
                               short* __restrict__ vT) {
  __shared__ short tile[64][65];
  int bh = blockIdx.x >> 4;
  int tc = blockIdx.x & 15;
  int b = bh >> 4, h = bh & 15;
  int t0 = tc * 64;
#pragma unroll
  for (int i = 0; i < 16; i++) {
    int p = threadIdx.x + i * 256;
    int tl = p >> 6, d = p & 63;
    tile[tl][d] = qkv[(size_t)(b * NT + t0 + tl) * C3 + 2 * NC + h * DH + d];
  }
  __syncthreads();
#pragma unroll
  for (int i = 0; i < 16; i++) {
    int p = threadIdx.x + i * 256;
    int dl = p >> 6, tl = p & 63;
    vT[(size_t)(bh * DH + dl) * NT + t0 + tl] = tile[tl][dl];
  }
}

// ---------------- flash attention (full, unmasked) -------------------------
// wave handles a 16-row q block; WG = 4 waves = 64 q rows; grid = 32*16
__global__ __launch_bounds__(256) void attn_kernel(const short* __restrict__ qkv,
                                                   const short* __restrict__ vT,
                                                   short* __restrict__ o) {
  __shared__ __attribute__((aligned(16))) float Pl[4][16][36];
  int wave = threadIdx.x >> 6, lane = threadIdx.x & 63;
  int quad = lane >> 4, l16 = lane & 15;
  int bh = blockIdx.x >> 4;
  int qchunk = blockIdx.x & 15;
  int b = bh >> 4, h = bh & 15;
  int q0 = qchunk * 64 + wave * 16;

  bf16x8 aq[2];
#pragma unroll
  for (int kk = 0; kk < 2; kk++) {
    const short* qp = qkv + (size_t)(b * NT + q0 + l16) * C3 + h * DH + kk * 32 + quad * 8;
    aq[kk] = *reinterpret_cast<const bf16x8*>(qp);
  }
  f32x4 oacc[4] = {};
  float mr[4], lr[4];
#pragma unroll
  for (int r = 0; r < 4; r++) { mr[r] = -INFINITY; lr[r] = 0.f; }

  for (int t0 = 0; t0 < NT; t0 += 32) {
    f32x4 s0 = {}, s1 = {};
#pragma unroll
    for (int kk = 0; kk < 2; kk++) {
      const short* kp0 = qkv + (size_t)(b * NT + t0 + l16) * C3 + NC + h * DH + kk * 32 + quad * 8;
      bf16x8 bk0 = *reinterpret_cast<const bf16x8*>(kp0);
      bf16x8 bk1 = *reinterpret_cast<const bf16x8*>(kp0 + (size_t)16 * C3);
      s0 = __builtin_amdgcn_mfma_f32_16x16x32_bf16(aq[kk], bk0, s0, 0, 0, 0);
      s1 = __builtin_amdgcn_mfma_f32_16x16x32_bf16(aq[kk], bk1, s1, 0, 0, 0);
    }
    float rm[4], p0[4], p1[4], alpha[4], rs[4];
#pragma unroll
    for (int r = 0; r < 4; r++) {
      s0[r] *= 0.125f;
      s1[r] *= 0.125f;
      rm[r] = fmaxf(s0[r], s1[r]);
    }
#pragma unroll
    for (int m = 1; m < 16; m <<= 1)
#pragma unroll
      for (int r = 0; r < 4; r++) rm[r] = fmaxf(rm[r], __shfl_xor(rm[r], m));
#pragma unroll
    for (int r = 0; r < 4; r++) {
      float mn = fmaxf(mr[r], rm[r]);
      alpha[r] = __expf(mr[r] - mn);
      mr[r] = mn;
      p0[r] = __expf(s0[r] - mn);
      p1[r] = __expf(s1[r] - mn);
      rs[r] = p0[r] + p1[r];
    }
#pragma unroll
    for (int m = 1; m < 16; m <<= 1)
#pragma unroll
      for (int r = 0; r < 4; r++) rs[r] += __shfl_xor(rs[r], m);
#pragma unroll
    for (int r = 0; r < 4; r++) lr[r] = lr[r] * alpha[r] + rs[r];
#pragma unroll
    for (int dt = 0; dt < 4; dt++)
#pragma unroll
      for (int r = 0; r < 4; r++) oacc[dt][r] *= alpha[r];
    // P (C-layout) -> LDS -> A-layout
#pragma unroll
    for (int r = 0; r < 4; r++) {
      Pl[wave][quad * 4 + r][l16] = p0[r];
      Pl[wave][quad * 4 + r][16 + l16] = p1[r];
    }
    __syncthreads();
    float4 pv0 = *reinterpret_cast<const float4*>(&Pl[wave][l16][quad * 8]);
    float4 pv1 = *reinterpret_cast<const float4*>(&Pl[wave][l16][quad * 8 + 4]);
    __syncthreads();
    bf16x8 pa = cvt8(pv0, pv1);
#pragma unroll
    for (int dt = 0; dt < 4; dt++) {
      const short* vp = vT + (size_t)(bh * DH + dt * 16 + l16) * NT + t0 + quad * 8;
      bf16x8 bv = *reinterpret_cast<const bf16x8*>(vp);
      oacc[dt] = __builtin_amdgcn_mfma_f32_16x16x32_bf16(pa, bv, oacc[dt], 0, 0, 0);
    }
  }
  float inv[4];
#pragma unroll
  for (int r = 0; r < 4; r++) inv[r] = 1.f / lr[r];
#pragma unroll
  for (int dt = 0; dt < 4; dt++)
#pragma unroll
    for (int r = 0; r < 4; r++) {
      int row = q0 + quad * 4 + r;
      o[(size_t)(b * NT + row) * NC + h * DH + dt * 16 + l16] = f2b(oacc[dt][r] * inv[r]);
    }
}

// ---------------- LM head: out[b,v] = dot(xf[b,:], wte[v,:]) ---------------
__global__ __launch_bounds__(256) void lmhead_kernel(const float* __restrict__ xf,
                                                     const float* __restrict__ wte,
                                                     float* __restrict__ out) {
  __shared__ float xs[2 * NC];
  for (int i = threadIdx.x; i < 2 * NC; i += 256) xs[i] = xf[i];
  __syncthreads();
  int wave = threadIdx.x >> 6, lane = threadIdx.x & 63;
  int wglobal = blockIdx.x * 4 + wave;
  int stride = gridDim.x * 4;
  for (int v = wglobal; v < NV; v += stride) {
    const float4* wr = reinterpret_cast<const float4*>(wte + (size_t)v * NC);
    float a0 = 0.f, a1 = 0.f;
#pragma unroll
    for (int i = 0; i < 4; i++) {
      int ci = lane + i * 64;
      float4 wv = wr[ci];
      float4 x0 = reinterpret_cast<const float4*>(xs)[ci];
      float4 x1 = reinterpret_cast<const float4*>(xs + NC)[ci];
      a0 += wv.x * x0.x + wv.y * x0.y + wv.z * x0.z + wv.w * x0.w;
      a1 += wv.x * x1.x + wv.y * x1.y + wv.z * x1.z + wv.w * x1.w;
    }
#pragma unroll
    for (int m = 32; m; m >>= 1) {
      a0 += __shfl_xor(a0, m);
      a1 += __shfl_xor(a1, m);
    }
    if (lane == 0) {
      out[v] = a0;
      out[NV + v] = a1;
    }
  }
}

// ---------------- host launch ----------------------------------------------
extern "C" void kernel_launch(void* const* d_in, const int* in_sizes, int n_in,
                              void* d_out, int out_size, void* d_ws, size_t ws_size,
                              hipStream_t stream) {
  const int* idx = (const int*)d_in[0];
  const float* wte = (const float*)d_in[1];
  const float* wpe = (const float*)d_in[2];
  const float* ln1_w = (const float*)d_in[3];
  const float* ln1_b = (const float*)d_in[4];
  const float* attn_w = (const float*)d_in[5];
  const float* attn_b = (const float*)d_in[6];
  const float* proj_w = (const float*)d_in[7];
  const float* proj_b = (const float*)d_in[8];
  const float* ln2_w = (const float*)d_in[9];
  const float* ln2_b = (const float*)d_in[10];
  const float* fc_w = (const float*)d_in[11];
  const float* fc_b = (const float*)d_in[12];
  const float* fc2_w = (const float*)d_in[13];
  const float* fc2_b = (const float*)d_in[14];
  const float* lnf_w = (const float*)d_in[15];
  const float* lnf_b = (const float*)d_in[16];

  char* ws = (char*)d_ws;
  size_t off = 0;
  float* x = (float*)(ws + off);  off += (size_t)NB * NT * NC * 4;   // 8 MB
  short* h = (short*)(ws + off);  off += (size_t)NB * NT * NC * 2;   // 4 MB
  short* qkv = (short*)(ws + off); off += (size_t)NB * NT * C3 * 2;  // 12.6 MB
  short* vT = (short*)(ws + off); off += (size_t)NB * NH * DH * NT * 2; // 4 MB
  short* o = (short*)(ws + off);  off += (size_t)NB * NT * NC * 2;   // 4 MB
  short* h2 = (short*)(ws + off); off += (size_t)NB * NT * C4 * 2;   // 16.8 MB
  float* xf = (float*)(ws + off); off += (size_t)2 * NC * 4;

  embed_kernel<<<NB * NT, 256, 0, stream>>>(idx, wte, wpe, x);

  for (int l = 0; l < NLAYER; l++) {
    ln_kernel<<<512, 256, 0, stream>>>(x, ln1_w + (size_t)l * NC, ln1_b + (size_t)l * NC, h);
    gemm_kernel<0><<<dim3(C3 / 64, 32), 256, 0, stream>>>(
        h, attn_w + (size_t)l * C3 * NC, attn_b + (size_t)l * C3, nullptr, qkv, C3, NC);
    vrepack_kernel<<<512, 256, 0, stream>>>(qkv, vT);
    attn_kernel<<<512, 256, 0, stream>>>(qkv, vT, o);
    gemm_kernel<1><<<dim3(NC / 64, 32), 256, 0, stream>>>(
        o, proj_w + (size_t)l * NC * NC, proj_b + (size_t)l * NC, x, nullptr, NC, NC);
    ln_kernel<<<512, 256, 0, stream>>>(x, ln2_w + (size_t)l * NC, ln2_b + (size_t)l * NC, h);
    gemm_kernel<2><<<dim3(C4 / 64, 32), 256, 0, stream>>>(
        h, fc_w + (size_t)l * C4 * NC, fc_b + (size_t)l * C4, nullptr, h2, C4, NC);
    gemm_kernel<1><<<dim3(NC / 64, 32), 256, 0, stream>>>(
        h2, fc2_w + (size_t)l * NC * C4, fc2_b + (size_t)l * NC, x, nullptr, NC, C4);
  }

  lnf_kernel<<<1, 128, 0, stream>>>(x, lnf_w, lnf_b, xf);
  lmhead_kernel<<<512, 256, 0, stream>>>(xf, wte, (float*)d_out);
}

// Round 2
// 1618.656 us; speedup vs baseline: 1.7308x; 1.7308x over previous
//
#include <hip/hip_runtime.h>
#include <hip/hip_bf16.h>

// GPT forward, B=2 T=1024 C=1024 L=4 H=16 HD=64 V=50257.
// Round 1: m97-style GEMM — 128x128 tile, LDS staging via global_load_lds
// width=16, per-layer fp32->bf16 weight pre-conversion.
//   - fp32 residual stream x in ws; activations bf16 at GEMM inputs
//   - attention: flash-style online softmax (unchanged this round)
//   - LM head: wave-per-row fp32 dot (memory bound)

constexpr int NB = 2;
constexpr int NT = 1024;
constexpr int NC = 1024;
constexpr int NLAYER = 4;
constexpr int NH = 16;
constexpr int DH = 64;
constexpr int NV = 50257;
constexpr int C3 = 3 * NC;
constexpr int C4 = 4 * NC;

typedef __attribute__((ext_vector_type(8))) short bf16x8;
typedef __attribute__((ext_vector_type(4))) float f32x4;
typedef __attribute__((ext_vector_type(4))) short s16x4;

__device__ inline short f2b(float x) {
  union { __hip_bfloat16 h; short s; } u;
  u.h = __float2bfloat16(x);
  return u.s;
}

__device__ inline bf16x8 cvt8(float4 a, float4 b) {
  bf16x8 r;
  r[0] = f2b(a.x); r[1] = f2b(a.y); r[2] = f2b(a.z); r[3] = f2b(a.w);
  r[4] = f2b(b.x); r[5] = f2b(b.y); r[6] = f2b(b.z); r[7] = f2b(b.w);
  return r;
}

__device__ inline void load_lds16(const short* gp, short* lp) {
  __builtin_amdgcn_global_load_lds(
      (const __attribute__((address_space(1))) void*)gp,
      (__attribute__((address_space(3))) void*)lp, 16, 0, 0);
}

// ---------------- fp32 -> bf16 weight conversion ---------------------------
__global__ __launch_bounds__(256) void cvt_kernel(const float* __restrict__ src,
                                                  short* __restrict__ dst, int n4) {
  int i = blockIdx.x * 256 + threadIdx.x;
  int stride = gridDim.x * 256;
  for (; i < n4; i += stride) {
    float4 v = reinterpret_cast<const float4*>(src)[i];
    s16x4 o;
    o[0] = f2b(v.x); o[1] = f2b(v.y); o[2] = f2b(v.z); o[3] = f2b(v.w);
    reinterpret_cast<s16x4*>(dst)[i] = o;
  }
}

// ---------------- embedding: x[b,t,:] = wte[idx[b,t],:] + wpe[t,:] ---------
__global__ void embed_kernel(const int* __restrict__ idx,
                             const float* __restrict__ wte,
                             const float* __restrict__ wpe,
                             float* __restrict__ x) {
  int row = blockIdx.x;
  int t = row & (NT - 1);
  int id = idx[row];
  const float4* wr = reinterpret_cast<const float4*>(wte + (size_t)id * NC);
  const float4* pr = reinterpret_cast<const float4*>(wpe + (size_t)t * NC);
  float4* xr = reinterpret_cast<float4*>(x + (size_t)row * NC);
  int i = threadIdx.x;
  float4 a = wr[i], b = pr[i];
  xr[i] = make_float4(a.x + b.x, a.y + b.y, a.z + b.z, a.w + b.w);
}

// ---------------- layernorm: wave per row, out bf16 ------------------------
__global__ __launch_bounds__(256) void ln_kernel(const float* __restrict__ x,
                                                 const float* __restrict__ w,
                                                 const float* __restrict__ bb,
                                                 short* __restrict__ out) {
  int wave = threadIdx.x >> 6;
  int lane = threadIdx.x & 63;
  int row = blockIdx.x * 4 + wave;
  const float4* xr = reinterpret_cast<const float4*>(x + (size_t)row * NC);
  float4 v[4];
  float s = 0.f;
#pragma unroll
  for (int i = 0; i < 4; i++) {
    v[i] = xr[lane + i * 64];
    s += v[i].x + v[i].y + v[i].z + v[i].w;
  }
#pragma unroll
  for (int m = 32; m; m >>= 1) s += __shfl_xor(s, m);
  float mean = s * (1.f / NC);
  float vs = 0.f;
#pragma unroll
  for (int i = 0; i < 4; i++) {
    float a = v[i].x - mean, b = v[i].y - mean, c = v[i].z - mean, d = v[i].w - mean;
    vs += a * a + b * b + c * c + d * d;
  }
#pragma unroll
  for (int m = 32; m; m >>= 1) vs += __shfl_xor(vs, m);
  float rstd = rsqrtf(vs * (1.f / NC) + 1e-5f);
  const float4* wr = reinterpret_cast<const float4*>(w);
  const float4* br = reinterpret_cast<const float4*>(bb);
  s16x4* orow = reinterpret_cast<s16x4*>(out + (size_t)row * NC);
#pragma unroll
  for (int i = 0; i < 4; i++) {
    int ci = lane + i * 64;
    float4 wv = wr[ci], bv = br[ci];
    s16x4 o;
    o[0] = f2b((v[i].x - mean) * rstd * wv.x + bv.x);
    o[1] = f2b((v[i].y - mean) * rstd * wv.y + bv.y);
    o[2] = f2b((v[i].z - mean) * rstd * wv.z + bv.z);
    o[3] = f2b((v[i].w - mean) * rstd * wv.w + bv.w);
    orow[ci] = o;
  }
}

// ---------------- final LN of x[b, NT-1, :] -> xf (fp32) -------------------
__global__ void lnf_kernel(const float* __restrict__ x,
                           const float* __restrict__ w,
                           const float* __restrict__ bb,
                           float* __restrict__ xf) {
  int wave = threadIdx.x >> 6;
  int lane = threadIdx.x & 63;
  size_t row = (size_t)wave * NT + (NT - 1);
  const float4* xr = reinterpret_cast<const float4*>(x + row * NC);
  float4 v[4];
  float s = 0.f;
#pragma unroll
  for (int i = 0; i < 4; i++) {
    v[i] = xr[lane + i * 64];
    s += v[i].x + v[i].y + v[i].z + v[i].w;
  }
#pragma unroll
  for (int m = 32; m; m >>= 1) s += __shfl_xor(s, m);
  float mean = s * (1.f / NC);
  float vs = 0.f;
#pragma unroll
  for (int i = 0; i < 4; i++) {
    float a = v[i].x - mean, b = v[i].y - mean, c = v[i].z - mean, d = v[i].w - mean;
    vs += a * a + b * b + c * c + d * d;
  }
#pragma unroll
  for (int m = 32; m; m >>= 1) vs += __shfl_xor(vs, m);
  float rstd = rsqrtf(vs * (1.f / NC) + 1e-5f);
  const float4* wr = reinterpret_cast<const float4*>(w);
  const float4* br = reinterpret_cast<const float4*>(bb);
  float4* orow = reinterpret_cast<float4*>(xf + (size_t)wave * NC);
#pragma unroll
  for (int i = 0; i < 4; i++) {
    int ci = lane + i * 64;
    float4 wv = wr[ci], bv = br[ci];
    float4 o;
    o.x = (v[i].x - mean) * rstd * wv.x + bv.x;
    o.y = (v[i].y - mean) * rstd * wv.y + bv.y;
    o.z = (v[i].z - mean) * rstd * wv.z + bv.z;
    o.w = (v[i].w - mean) * rstd * wv.w + bv.w;
    orow[ci] = o;
  }
}

// ---------------- GEMM: out = A(bf16,[2048 x K]) @ Wb(bf16,[N x K])^T + b --
// m97 structure: 128x128 tile, BK=32, 4 waves x (4x4) 16x16x32 frags,
// global_load_lds width-16 staging, 2-barrier K-loop.
// EPI: 0 = store bf16, 1 = residual add into f32 buffer, 2 = GELU -> bf16
template <int EPI>
__global__ __launch_bounds__(256) void gemm_kernel(
    const short* __restrict__ A, const short* __restrict__ Wb,
    const float* __restrict__ bias, float* __restrict__ outF,
    short* __restrict__ outB, int N, int K) {
  __shared__ short As[128 * 32];
  __shared__ short Bs[128 * 32];
  int tid = threadIdx.x;
  int lane = tid & 63;
  int wave = tid >> 6;
  int quad = lane >> 4, l16 = lane & 15;
  int wm = (wave >> 1) * 64;          // wave's 64x64 quadrant
  int wn = (wave & 1) * 64;
  const short* Ab = A + (size_t)(blockIdx.y * 128) * K;
  const short* Bb = Wb + (size_t)(blockIdx.x * 128) * K;

  f32x4 acc[4][4] = {};
  for (int k0 = 0; k0 < K; k0 += 32) {
    // stage A,B 128x32 tiles: 512 chunks of 16B each, 2 per thread per tile
#pragma unroll
    for (int u = 0; u < 2; u++) {
      int c = tid + u * 256;
      int row = c >> 2, kc = (c & 3) * 8;
      load_lds16(Ab + (size_t)row * K + k0 + kc, As + c * 8);
      load_lds16(Bb + (size_t)row * K + k0 + kc, Bs + c * 8);
    }
    __syncthreads();
    bf16x8 a[4], b[4];
#pragma unroll
    for (int i = 0; i < 4; i++)
      a[i] = *reinterpret_cast<const bf16x8*>(As + (wm + i * 16 + l16) * 32 + quad * 8);
#pragma unroll
    for (int j = 0; j < 4; j++)
      b[j] = *reinterpret_cast<const bf16x8*>(Bs + (wn + j * 16 + l16) * 32 + quad * 8);
#pragma unroll
    for (int i = 0; i < 4; i++)
#pragma unroll
      for (int j = 0; j < 4; j++)
        acc[i][j] = __builtin_amdgcn_mfma_f32_16x16x32_bf16(a[i], b[j], acc[i][j], 0, 0, 0);
    __syncthreads();
  }
#pragma unroll
  for (int j = 0; j < 4; j++) {
    int col = blockIdx.x * 128 + wn + j * 16 + l16;
    float bv = bias[col];
#pragma unroll
    for (int i = 0; i < 4; i++) {
#pragma unroll
      for (int r = 0; r < 4; r++) {
        int row = blockIdx.y * 128 + wm + i * 16 + quad * 4 + r;
        float vv = acc[i][j][r] + bv;
        size_t off = (size_t)row * N + col;
        if constexpr (EPI == 0) {
          outB[off] = f2b(vv);
        } else if constexpr (EPI == 1) {
          outF[off] += vv;
        } else {
          float g = 0.5f * vv * (1.f + erff(vv * 0.70710678f));
          outB[off] = f2b(g);
        }
      }
    }
  }
}

// ---------------- V transpose: qkv v-part -> vT[bh, d, t] bf16 -------------
__global__ void vrepack_kernel(const short* __restrict__ qkv,
                               short* __restrict__ vT) {
  __shared__ short tile[64][65];
  int bh = blockIdx.x >> 4;
  int tc = blockIdx.x & 15;
  int b = bh >> 4, h = bh & 15;
  int t0 = tc * 64;
#pragma unroll
  for (int i = 0; i < 16; i++) {
    int p = threadIdx.x + i * 256;
    int tl = p >> 6, d = p & 63;
    tile[tl][d] = qkv[(size_t)(b * NT + t0 + tl) * C3 + 2 * NC + h * DH + d];
  }
  __syncthreads();
#pragma unroll
  for (int i = 0; i < 16; i++) {
    int p = threadIdx.x + i * 256;
    int dl = p >> 6, tl = p & 63;
    vT[(size_t)(bh * DH + dl) * NT + t0 + tl] = tile[tl][dl];
  }
}

// ---------------- flash attention (full, unmasked) -------------------------
__global__ __launch_bounds__(256) void attn_kernel(const short* __restrict__ qkv,
                                                   const short* __restrict__ vT,
                                                   short* __restrict__ o) {
  __shared__ __attribute__((aligned(16))) float Pl[4][16][36];
  int wave = threadIdx.x >> 6, lane = threadIdx.x & 63;
  int quad = lane >> 4, l16 = lane & 15;
  int bh = blockIdx.x >> 4;
  int qchunk = blockIdx.x & 15;
  int b = bh >> 4, h = bh & 15;
  int q0 = qchunk * 64 + wave * 16;

  bf16x8 aq[2];
#pragma unroll
  for (int kk = 0; kk < 2; kk++) {
    const short* qp = qkv + (size_t)(b * NT + q0 + l16) * C3 + h * DH + kk * 32 + quad * 8;
    aq[kk] = *reinterpret_cast<const bf16x8*>(qp);
  }
  f32x4 oacc[4] = {};
  float mr[4], lr[4];
#pragma unroll
  for (int r = 0; r < 4; r++) { mr[r] = -INFINITY; lr[r] = 0.f; }

  for (int t0 = 0; t0 < NT; t0 += 32) {
    f32x4 s0 = {}, s1 = {};
#pragma unroll
    for (int kk = 0; kk < 2; kk++) {
      const short* kp0 = qkv + (size_t)(b * NT + t0 + l16) * C3 + NC + h * DH + kk * 32 + quad * 8;
      bf16x8 bk0 = *reinterpret_cast<const bf16x8*>(kp0);
      bf16x8 bk1 = *reinterpret_cast<const bf16x8*>(kp0 + (size_t)16 * C3);
      s0 = __builtin_amdgcn_mfma_f32_16x16x32_bf16(aq[kk], bk0, s0, 0, 0, 0);
      s1 = __builtin_amdgcn_mfma_f32_16x16x32_bf16(aq[kk], bk1, s1, 0, 0, 0);
    }
    float rm[4], p0[4], p1[4], alpha[4], rs[4];
#pragma unroll
    for (int r = 0; r < 4; r++) {
      s0[r] *= 0.125f;
      s1[r] *= 0.125f;
      rm[r] = fmaxf(s0[r], s1[r]);
    }
#pragma unroll
    for (int m = 1; m < 16; m <<= 1)
#pragma unroll
      for (int r = 0; r < 4; r++) rm[r] = fmaxf(rm[r], __shfl_xor(rm[r], m));
#pragma unroll
    for (int r = 0; r < 4; r++) {
      float mn = fmaxf(mr[r], rm[r]);
      alpha[r] = __expf(mr[r] - mn);
      mr[r] = mn;
      p0[r] = __expf(s0[r] - mn);
      p1[r] = __expf(s1[r] - mn);
      rs[r] = p0[r] + p1[r];
    }
#pragma unroll
    for (int m = 1; m < 16; m <<= 1)
#pragma unroll
      for (int r = 0; r < 4; r++) rs[r] += __shfl_xor(rs[r], m);
#pragma unroll
    for (int r = 0; r < 4; r++) lr[r] = lr[r] * alpha[r] + rs[r];
#pragma unroll
    for (int dt = 0; dt < 4; dt++)
#pragma unroll
      for (int r = 0; r < 4; r++) oacc[dt][r] *= alpha[r];
#pragma unroll
    for (int r = 0; r < 4; r++) {
      Pl[wave][quad * 4 + r][l16] = p0[r];
      Pl[wave][quad * 4 + r][16 + l16] = p1[r];
    }
    __syncthreads();
    float4 pv0 = *reinterpret_cast<const float4*>(&Pl[wave][l16][quad * 8]);
    float4 pv1 = *reinterpret_cast<const float4*>(&Pl[wave][l16][quad * 8 + 4]);
    __syncthreads();
    bf16x8 pa = cvt8(pv0, pv1);
#pragma unroll
    for (int dt = 0; dt < 4; dt++) {
      const short* vp = vT + (size_t)(bh * DH + dt * 16 + l16) * NT + t0 + quad * 8;
      bf16x8 bv = *reinterpret_cast<const bf16x8*>(vp);
      oacc[dt] = __builtin_amdgcn_mfma_f32_16x16x32_bf16(pa, bv, oacc[dt], 0, 0, 0);
    }
  }
  float inv[4];
#pragma unroll
  for (int r = 0; r < 4; r++) inv[r] = 1.f / lr[r];
#pragma unroll
  for (int dt = 0; dt < 4; dt++)
#pragma unroll
    for (int r = 0; r < 4; r++) {
      int row = q0 + quad * 4 + r;
      o[(size_t)(b * NT + row) * NC + h * DH + dt * 16 + l16] = f2b(oacc[dt][r] * inv[r]);
    }
}

// ---------------- LM head: out[b,v] = dot(xf[b,:], wte[v,:]) ---------------
__global__ __launch_bounds__(256) void lmhead_kernel(const float* __restrict__ xf,
                                                     const float* __restrict__ wte,
                                                     float* __restrict__ out) {
  __shared__ float xs[2 * NC];
  for (int i = threadIdx.x; i < 2 * NC; i += 256) xs[i] = xf[i];
  __syncthreads();
  int wave = threadIdx.x >> 6, lane = threadIdx.x & 63;
  int wglobal = blockIdx.x * 4 + wave;
  int stride = gridDim.x * 4;
  for (int v = wglobal; v < NV; v += stride) {
    const float4* wr = reinterpret_cast<const float4*>(wte + (size_t)v * NC);
    float a0 = 0.f, a1 = 0.f;
#pragma unroll
    for (int i = 0; i < 4; i++) {
      int ci = lane + i * 64;
      float4 wv = wr[ci];
      float4 x0 = reinterpret_cast<const float4*>(xs)[ci];
      float4 x1 = reinterpret_cast<const float4*>(xs + NC)[ci];
      a0 += wv.x * x0.x + wv.y * x0.y + wv.z * x0.z + wv.w * x0.w;
      a1 += wv.x * x1.x + wv.y * x1.y + wv.z * x1.z + wv.w * x1.w;
    }
#pragma unroll
    for (int m = 32; m; m >>= 1) {
      a0 += __shfl_xor(a0, m);
      a1 += __shfl_xor(a1, m);
    }
    if (lane == 0) {
      out[v] = a0;
      out[NV + v] = a1;
    }
  }
}

// ---------------- host launch ----------------------------------------------
extern "C" void kernel_launch(void* const* d_in, const int* in_sizes, int n_in,
                              void* d_out, int out_size, void* d_ws, size_t ws_size,
                              hipStream_t stream) {
  const int* idx = (const int*)d_in[0];
  const float* wte = (const float*)d_in[1];
  const float* wpe = (const float*)d_in[2];
  const float* ln1_w = (const float*)d_in[3];
  const float* ln1_b = (const float*)d_in[4];
  const float* attn_w = (const float*)d_in[5];
  const float* attn_b = (const float*)d_in[6];
  const float* proj_w = (const float*)d_in[7];
  const float* proj_b = (const float*)d_in[8];
  const float* ln2_w = (const float*)d_in[9];
  const float* ln2_b = (const float*)d_in[10];
  const float* fc_w = (const float*)d_in[11];
  const float* fc_b = (const float*)d_in[12];
  const float* fc2_w = (const float*)d_in[13];
  const float* fc2_b = (const float*)d_in[14];
  const float* lnf_w = (const float*)d_in[15];
  const float* lnf_b = (const float*)d_in[16];

  char* ws = (char*)d_ws;
  size_t off = 0;
  float* x = (float*)(ws + off);  off += (size_t)NB * NT * NC * 4;       // 8 MB
  short* h = (short*)(ws + off);  off += (size_t)NB * NT * NC * 2;       // 4 MB
  short* qkv = (short*)(ws + off); off += (size_t)NB * NT * C3 * 2;      // 12.6 MB
  short* vT = (short*)(ws + off); off += (size_t)NB * NH * DH * NT * 2;  // 4 MB
  short* o = (short*)(ws + off);  off += (size_t)NB * NT * NC * 2;       // 4 MB
  short* h2 = (short*)(ws + off); off += (size_t)NB * NT * C4 * 2;       // 16.8 MB
  float* xf = (float*)(ws + off); off += (size_t)2 * NC * 4;
  // per-layer bf16 weights (reused across layers)
  short* wb_attn = (short*)(ws + off); off += (size_t)C3 * NC * 2;       // 6.3 MB
  short* wb_proj = (short*)(ws + off); off += (size_t)NC * NC * 2;       // 2.1 MB
  short* wb_fc = (short*)(ws + off);   off += (size_t)C4 * NC * 2;       // 8.4 MB
  short* wb_fc2 = (short*)(ws + off);  off += (size_t)NC * C4 * 2;       // 8.4 MB

  embed_kernel<<<NB * NT, 256, 0, stream>>>(idx, wte, wpe, x);

  for (int l = 0; l < NLAYER; l++) {
    cvt_kernel<<<512, 256, 0, stream>>>(attn_w + (size_t)l * C3 * NC, wb_attn, C3 * NC / 4);
    cvt_kernel<<<512, 256, 0, stream>>>(proj_w + (size_t)l * NC * NC, wb_proj, NC * NC / 4);
    cvt_kernel<<<512, 256, 0, stream>>>(fc_w + (size_t)l * C4 * NC, wb_fc, C4 * NC / 4);
    cvt_kernel<<<512, 256, 0, stream>>>(fc2_w + (size_t)l * NC * C4, wb_fc2, NC * C4 / 4);

    ln_kernel<<<512, 256, 0, stream>>>(x, ln1_w + (size_t)l * NC, ln1_b + (size_t)l * NC, h);
    gemm_kernel<0><<<dim3(C3 / 128, 16), 256, 0, stream>>>(
        h, wb_attn, attn_b + (size_t)l * C3, nullptr, qkv, C3, NC);
    vrepack_kernel<<<512, 256, 0, stream>>>(qkv, vT);
    attn_kernel<<<512, 256, 0, stream>>>(qkv, vT, o);
    gemm_kernel<1><<<dim3(NC / 128, 16), 256, 0, stream>>>(
        o, wb_proj, proj_b + (size_t)l * NC, x, nullptr, NC, NC);
    ln_kernel<<<512, 256, 0, stream>>>(x, ln2_w + (size_t)l * NC, ln2_b + (size_t)l * NC, h);
    gemm_kernel<2><<<dim3(C4 / 128, 16), 256, 0, stream>>>(
        h, wb_fc, fc_b + (size_t)l * C4, nullptr, h2, C4, NC);
    gemm_kernel<1><<<dim3(NC / 128, 16), 256, 0, stream>>>(
        h2, wb_fc2, fc2_b + (size_t)l * NC, x, nullptr, NC, C4);
  }

  lnf_kernel<<<1, 128, 0, stream>>>(x, lnf_w, lnf_b, xf);
  lmhead_kernel<<<512, 256, 0, stream>>>(xf, wte, (float*)d_out);
}

// Round 3
// 1325.347 us; speedup vs baseline: 2.1139x; 1.2213x over previous
//
#include <hip/hip_runtime.h>
#include <hip/hip_bf16.h>

// GPT forward, B=2 T=1024 C=1024 L=4 H=16 HD=64 V=50257.
// Round 2: BK=64 GEMM (32 MFMA/barrier), 64x64 tiles for N=1024 GEMMs
// (512 blocks vs 128), cvt merged to 4 dispatches, vrepack fused into qkv
// epilogue, lnf fused into lmhead.

constexpr int NB = 2;
constexpr int NT = 1024;
constexpr int NC = 1024;
constexpr int NLAYER = 4;
constexpr int NH = 16;
constexpr int DH = 64;
constexpr int NV = 50257;
constexpr int C3 = 3 * NC;
constexpr int C4 = 4 * NC;

typedef __attribute__((ext_vector_type(8))) short bf16x8;
typedef __attribute__((ext_vector_type(4))) float f32x4;
typedef __attribute__((ext_vector_type(4))) short s16x4;

__device__ inline short f2b(float x) {
  union { __hip_bfloat16 h; short s; } u;
  u.h = __float2bfloat16(x);
  return u.s;
}

__device__ inline bf16x8 cvt8(float4 a, float4 b) {
  bf16x8 r;
  r[0] = f2b(a.x); r[1] = f2b(a.y); r[2] = f2b(a.z); r[3] = f2b(a.w);
  r[4] = f2b(b.x); r[5] = f2b(b.y); r[6] = f2b(b.z); r[7] = f2b(b.w);
  return r;
}

__device__ inline void load_lds16(const short* gp, short* lp) {
  __builtin_amdgcn_global_load_lds(
      (const __attribute__((address_space(1))) void*)gp,
      (__attribute__((address_space(3))) void*)lp, 16, 0, 0);
}

// ---------------- fp32 -> bf16 weight conversion (whole tensor) ------------
__global__ __launch_bounds__(256) void cvt_kernel(const float* __restrict__ src,
                                                  short* __restrict__ dst, int n4) {
  int i = blockIdx.x * 256 + threadIdx.x;
  int stride = gridDim.x * 256;
  for (; i < n4; i += stride) {
    float4 v = reinterpret_cast<const float4*>(src)[i];
    s16x4 o;
    o[0] = f2b(v.x); o[1] = f2b(v.y); o[2] = f2b(v.z); o[3] = f2b(v.w);
    reinterpret_cast<s16x4*>(dst)[i] = o;
  }
}

// ---------------- embedding: x[b,t,:] = wte[idx[b,t],:] + wpe[t,:] ---------
__global__ void embed_kernel(const int* __restrict__ idx,
                             const float* __restrict__ wte,
                             const float* __restrict__ wpe,
                             float* __restrict__ x) {
  int row = blockIdx.x;
  int t = row & (NT - 1);
  int id = idx[row];
  const float4* wr = reinterpret_cast<const float4*>(wte + (size_t)id * NC);
  const float4* pr = reinterpret_cast<const float4*>(wpe + (size_t)t * NC);
  float4* xr = reinterpret_cast<float4*>(x + (size_t)row * NC);
  int i = threadIdx.x;
  float4 a = wr[i], b = pr[i];
  xr[i] = make_float4(a.x + b.x, a.y + b.y, a.z + b.z, a.w + b.w);
}

// ---------------- layernorm: wave per row, out bf16 ------------------------
__global__ __launch_bounds__(256) void ln_kernel(const float* __restrict__ x,
                                                 const float* __restrict__ w,
                                                 const float* __restrict__ bb,
                                                 short* __restrict__ out) {
  int wave = threadIdx.x >> 6;
  int lane = threadIdx.x & 63;
  int row = blockIdx.x * 4 + wave;
  const float4* xr = reinterpret_cast<const float4*>(x + (size_t)row * NC);
  float4 v[4];
  float s = 0.f;
#pragma unroll
  for (int i = 0; i < 4; i++) {
    v[i] = xr[lane + i * 64];
    s += v[i].x + v[i].y + v[i].z + v[i].w;
  }
#pragma unroll
  for (int m = 32; m; m >>= 1) s += __shfl_xor(s, m);
  float mean = s * (1.f / NC);
  float vs = 0.f;
#pragma unroll
  for (int i = 0; i < 4; i++) {
    float a = v[i].x - mean, b = v[i].y - mean, c = v[i].z - mean, d = v[i].w - mean;
    vs += a * a + b * b + c * c + d * d;
  }
#pragma unroll
  for (int m = 32; m; m >>= 1) vs += __shfl_xor(vs, m);
  float rstd = rsqrtf(vs * (1.f / NC) + 1e-5f);
  const float4* wr = reinterpret_cast<const float4*>(w);
  const float4* br = reinterpret_cast<const float4*>(bb);
  s16x4* orow = reinterpret_cast<s16x4*>(out + (size_t)row * NC);
#pragma unroll
  for (int i = 0; i < 4; i++) {
    int ci = lane + i * 64;
    float4 wv = wr[ci], bv = br[ci];
    s16x4 o;
    o[0] = f2b((v[i].x - mean) * rstd * wv.x + bv.x);
    o[1] = f2b((v[i].y - mean) * rstd * wv.y + bv.y);
    o[2] = f2b((v[i].z - mean) * rstd * wv.z + bv.z);
    o[3] = f2b((v[i].w - mean) * rstd * wv.w + bv.w);
    orow[ci] = o;
  }
}

// ---------------- GEMM: out = A(bf16,[2048 x K]) @ Wb(bf16,[N x K])^T + b --
// BK=64, [kstep][row][32] LDS sub-tiles (m97 frag pattern per kstep),
// global_load_lds width-16 staging, 2-barrier K-loop, 32 MFMA/wave/barrier.
// EPI: 0 = store bf16 (+ fused vT transpose for V columns),
//      1 = residual add into f32 buffer, 2 = GELU -> bf16
template <int BM, int BN, int EPI>
__global__ __launch_bounds__(256) void gemm_kernel(
    const short* __restrict__ A, const short* __restrict__ Wb,
    const float* __restrict__ bias, float* __restrict__ outF,
    short* __restrict__ outB, short* __restrict__ vT, int N, int K) {
  constexpr int WM = BM / 2, WN = BN / 2;
  constexpr int FM = WM / 16, FN = WN / 16;
  constexpr int CA = BM * 8;           // 16B chunks per A tile (BK=64)
  constexpr int CB = BN * 8;
  constexpr int CT = CA + CB;
  __shared__ short As[2 * BM * 32];
  __shared__ short Bs[2 * BN * 32];
  int tid = threadIdx.x;
  int lane = tid & 63;
  int wave = tid >> 6;
  int quad = lane >> 4, l16 = lane & 15;
  int wm = (wave >> 1) * WM;
  int wn = (wave & 1) * WN;
  const short* Ab = A + (size_t)(blockIdx.y * BM) * K;
  const short* Bb = Wb + (size_t)(blockIdx.x * BN) * K;

  f32x4 acc[FM][FN] = {};
  for (int k0 = 0; k0 < K; k0 += 64) {
#pragma unroll
    for (int u = 0; u < CT / 256; u++) {
      int c = tid + u * 256;
      if (c < CA) {
        int ks = c / (CA / 2), rem = c % (CA / 2);
        int row = rem >> 2, kc = (rem & 3) * 8;
        load_lds16(Ab + (size_t)row * K + k0 + ks * 32 + kc, As + c * 8);
      } else {
        int c2 = c - CA;
        int ks = c2 / (CB / 2), rem = c2 % (CB / 2);
        int row = rem >> 2, kc = (rem & 3) * 8;
        load_lds16(Bb + (size_t)row * K + k0 + ks * 32 + kc, Bs + c2 * 8);
      }
    }
    __syncthreads();
#pragma unroll
    for (int s = 0; s < 2; s++) {
      bf16x8 a[FM], b[FN];
#pragma unroll
      for (int i = 0; i < FM; i++)
        a[i] = *reinterpret_cast<const bf16x8*>(As + s * BM * 32 + (wm + i * 16 + l16) * 32 + quad * 8);
#pragma unroll
      for (int j = 0; j < FN; j++)
        b[j] = *reinterpret_cast<const bf16x8*>(Bs + s * BN * 32 + (wn + j * 16 + l16) * 32 + quad * 8);
#pragma unroll
      for (int i = 0; i < FM; i++)
#pragma unroll
        for (int j = 0; j < FN; j++)
          acc[i][j] = __builtin_amdgcn_mfma_f32_16x16x32_bf16(a[i], b[j], acc[i][j], 0, 0, 0);
    }
    __syncthreads();
  }
#pragma unroll
  for (int j = 0; j < FN; j++) {
    int col = blockIdx.x * BN + wn + j * 16 + l16;
    float bv = bias[col];
#pragma unroll
    for (int i = 0; i < FM; i++) {
#pragma unroll
      for (int r = 0; r < 4; r++) {
        int row = blockIdx.y * BM + wm + i * 16 + quad * 4 + r;
        float vv = acc[i][j][r] + bv;
        size_t off = (size_t)row * N + col;
        if constexpr (EPI == 0) {
          short sv = f2b(vv);
          outB[off] = sv;
          if (col >= 2 * NC) {   // fused V transpose: vT[bh, d, t]
            int cg = col - 2 * NC;
            int hh = cg >> 6, d = cg & 63;
            int b = row >> 10, t = row & (NT - 1);
            vT[(size_t)(((b << 4) | hh) * DH + d) * NT + t] = sv;
          }
        } else if constexpr (EPI == 1) {
          outF[off] += vv;
        } else {
          float g = 0.5f * vv * (1.f + erff(vv * 0.70710678f));
          outB[off] = f2b(g);
        }
      }
    }
  }
}

// ---------------- flash attention (full, unmasked) -------------------------
__global__ __launch_bounds__(256) void attn_kernel(const short* __restrict__ qkv,
                                                   const short* __restrict__ vT,
                                                   short* __restrict__ o) {
  __shared__ __attribute__((aligned(16))) float Pl[4][16][36];
  int wave = threadIdx.x >> 6, lane = threadIdx.x & 63;
  int quad = lane >> 4, l16 = lane & 15;
  int bh = blockIdx.x >> 4;
  int qchunk = blockIdx.x & 15;
  int b = bh >> 4, h = bh & 15;
  int q0 = qchunk * 64 + wave * 16;

  bf16x8 aq[2];
#pragma unroll
  for (int kk = 0; kk < 2; kk++) {
    const short* qp = qkv + (size_t)(b * NT + q0 + l16) * C3 + h * DH + kk * 32 + quad * 8;
    aq[kk] = *reinterpret_cast<const bf16x8*>(qp);
  }
  f32x4 oacc[4] = {};
  float mr[4], lr[4];
#pragma unroll
  for (int r = 0; r < 4; r++) { mr[r] = -INFINITY; lr[r] = 0.f; }

  for (int t0 = 0; t0 < NT; t0 += 32) {
    f32x4 s0 = {}, s1 = {};
#pragma unroll
    for (int kk = 0; kk < 2; kk++) {
      const short* kp0 = qkv + (size_t)(b * NT + t0 + l16) * C3 + NC + h * DH + kk * 32 + quad * 8;
      bf16x8 bk0 = *reinterpret_cast<const bf16x8*>(kp0);
      bf16x8 bk1 = *reinterpret_cast<const bf16x8*>(kp0 + (size_t)16 * C3);
      s0 = __builtin_amdgcn_mfma_f32_16x16x32_bf16(aq[kk], bk0, s0, 0, 0, 0);
      s1 = __builtin_amdgcn_mfma_f32_16x16x32_bf16(aq[kk], bk1, s1, 0, 0, 0);
    }
    float rm[4], p0[4], p1[4], alpha[4], rs[4];
#pragma unroll
    for (int r = 0; r < 4; r++) {
      s0[r] *= 0.125f;
      s1[r] *= 0.125f;
      rm[r] = fmaxf(s0[r], s1[r]);
    }
#pragma unroll
    for (int m = 1; m < 16; m <<= 1)
#pragma unroll
      for (int r = 0; r < 4; r++) rm[r] = fmaxf(rm[r], __shfl_xor(rm[r], m));
#pragma unroll
    for (int r = 0; r < 4; r++) {
      float mn = fmaxf(mr[r], rm[r]);
      alpha[r] = __expf(mr[r] - mn);
      mr[r] = mn;
      p0[r] = __expf(s0[r] - mn);
      p1[r] = __expf(s1[r] - mn);
      rs[r] = p0[r] + p1[r];
    }
#pragma unroll
    for (int m = 1; m < 16; m <<= 1)
#pragma unroll
      for (int r = 0; r < 4; r++) rs[r] += __shfl_xor(rs[r], m);
#pragma unroll
    for (int r = 0; r < 4; r++) lr[r] = lr[r] * alpha[r] + rs[r];
#pragma unroll
    for (int dt = 0; dt < 4; dt++)
#pragma unroll
      for (int r = 0; r < 4; r++) oacc[dt][r] *= alpha[r];
#pragma unroll
    for (int r = 0; r < 4; r++) {
      Pl[wave][quad * 4 + r][l16] = p0[r];
      Pl[wave][quad * 4 + r][16 + l16] = p1[r];
    }
    __syncthreads();
    float4 pv0 = *reinterpret_cast<const float4*>(&Pl[wave][l16][quad * 8]);
    float4 pv1 = *reinterpret_cast<const float4*>(&Pl[wave][l16][quad * 8 + 4]);
    __syncthreads();
    bf16x8 pa = cvt8(pv0, pv1);
#pragma unroll
    for (int dt = 0; dt < 4; dt++) {
      const short* vp = vT + (size_t)(bh * DH + dt * 16 + l16) * NT + t0 + quad * 8;
      bf16x8 bv = *reinterpret_cast<const bf16x8*>(vp);
      oacc[dt] = __builtin_amdgcn_mfma_f32_16x16x32_bf16(pa, bv, oacc[dt], 0, 0, 0);
    }
  }
  float inv[4];
#pragma unroll
  for (int r = 0; r < 4; r++) inv[r] = 1.f / lr[r];
#pragma unroll
  for (int dt = 0; dt < 4; dt++)
#pragma unroll
    for (int r = 0; r < 4; r++) {
      int row = q0 + quad * 4 + r;
      o[(size_t)(b * NT + row) * NC + h * DH + dt * 16 + l16] = f2b(oacc[dt][r] * inv[r]);
    }
}

// ---------------- LM head (fused final LN): out[b,v] = lnf(x[b,-1]).wte[v] -
__global__ __launch_bounds__(256) void lmhead_kernel(const float* __restrict__ x,
                                                     const float* __restrict__ lnf_w,
                                                     const float* __restrict__ lnf_b,
                                                     const float* __restrict__ wte,
                                                     float* __restrict__ out) {
  __shared__ float xs[2 * NC];
  int wave = threadIdx.x >> 6, lane = threadIdx.x & 63;
  if (wave < 2) {
    size_t row = (size_t)wave * NT + (NT - 1);
    const float4* xr = reinterpret_cast<const float4*>(x + row * NC);
    float4 v[4];
    float s = 0.f;
#pragma unroll
    for (int i = 0; i < 4; i++) {
      v[i] = xr[lane + i * 64];
      s += v[i].x + v[i].y + v[i].z + v[i].w;
    }
#pragma unroll
    for (int m = 32; m; m >>= 1) s += __shfl_xor(s, m);
    float mean = s * (1.f / NC);
    float vs = 0.f;
#pragma unroll
    for (int i = 0; i < 4; i++) {
      float a = v[i].x - mean, b = v[i].y - mean, c = v[i].z - mean, d = v[i].w - mean;
      vs += a * a + b * b + c * c + d * d;
    }
#pragma unroll
    for (int m = 32; m; m >>= 1) vs += __shfl_xor(vs, m);
    float rstd = rsqrtf(vs * (1.f / NC) + 1e-5f);
    const float4* wr = reinterpret_cast<const float4*>(lnf_w);
    const float4* br = reinterpret_cast<const float4*>(lnf_b);
#pragma unroll
    for (int i = 0; i < 4; i++) {
      int ci = lane + i * 64;
      float4 wv = wr[ci], bv = br[ci];
      float4 o;
      o.x = (v[i].x - mean) * rstd * wv.x + bv.x;
      o.y = (v[i].y - mean) * rstd * wv.y + bv.y;
      o.z = (v[i].z - mean) * rstd * wv.z + bv.z;
      o.w = (v[i].w - mean) * rstd * wv.w + bv.w;
      reinterpret_cast<float4*>(xs + wave * NC)[ci] = o;
    }
  }
  __syncthreads();
  int wglobal = blockIdx.x * 4 + wave;
  int stride = gridDim.x * 4;
  for (int v = wglobal; v < NV; v += stride) {
    const float4* wr = reinterpret_cast<const float4*>(wte + (size_t)v * NC);
    float a0 = 0.f, a1 = 0.f;
#pragma unroll
    for (int i = 0; i < 4; i++) {
      int ci = lane + i * 64;
      float4 wv = wr[ci];
      float4 x0 = reinterpret_cast<const float4*>(xs)[ci];
      float4 x1 = reinterpret_cast<const float4*>(xs + NC)[ci];
      a0 += wv.x * x0.x + wv.y * x0.y + wv.z * x0.z + wv.w * x0.w;
      a1 += wv.x * x1.x + wv.y * x1.y + wv.z * x1.z + wv.w * x1.w;
    }
#pragma unroll
    for (int m = 32; m; m >>= 1) {
      a0 += __shfl_xor(a0, m);
      a1 += __shfl_xor(a1, m);
    }
    if (lane == 0) {
      out[v] = a0;
      out[NV + v] = a1;
    }
  }
}

// ---------------- host launch ----------------------------------------------
extern "C" void kernel_launch(void* const* d_in, const int* in_sizes, int n_in,
                              void* d_out, int out_size, void* d_ws, size_t ws_size,
                              hipStream_t stream) {
  const int* idx = (const int*)d_in[0];
  const float* wte = (const float*)d_in[1];
  const float* wpe = (const float*)d_in[2];
  const float* ln1_w = (const float*)d_in[3];
  const float* ln1_b = (const float*)d_in[4];
  const float* attn_w = (const float*)d_in[5];
  const float* attn_b = (const float*)d_in[6];
  const float* proj_w = (const float*)d_in[7];
  const float* proj_b = (const float*)d_in[8];
  const float* ln2_w = (const float*)d_in[9];
  const float* ln2_b = (const float*)d_in[10];
  const float* fc_w = (const float*)d_in[11];
  const float* fc_b = (const float*)d_in[12];
  const float* fc2_w = (const float*)d_in[13];
  const float* fc2_b = (const float*)d_in[14];
  const float* lnf_w = (const float*)d_in[15];
  const float* lnf_b = (const float*)d_in[16];

  char* ws = (char*)d_ws;
  size_t off = 0;
  float* x = (float*)(ws + off);  off += (size_t)NB * NT * NC * 4;       // 8 MB
  short* h = (short*)(ws + off);  off += (size_t)NB * NT * NC * 2;       // 4 MB
  short* qkv = (short*)(ws + off); off += (size_t)NB * NT * C3 * 2;      // 12.6 MB
  short* vT = (short*)(ws + off); off += (size_t)NB * NH * DH * NT * 2;  // 4 MB
  short* o = (short*)(ws + off);  off += (size_t)NB * NT * NC * 2;       // 4 MB
  short* h2 = (short*)(ws + off); off += (size_t)NB * NT * C4 * 2;       // 16.8 MB
  // bf16 weights, all layers
  short* wb_attn = (short*)(ws + off); off += (size_t)NLAYER * C3 * NC * 2;  // 25 MB
  short* wb_proj = (short*)(ws + off); off += (size_t)NLAYER * NC * NC * 2;  // 8.4 MB
  short* wb_fc = (short*)(ws + off);   off += (size_t)NLAYER * C4 * NC * 2;  // 33.6 MB
  short* wb_fc2 = (short*)(ws + off);  off += (size_t)NLAYER * NC * C4 * 2;  // 33.6 MB

  cvt_kernel<<<2048, 256, 0, stream>>>(attn_w, wb_attn, NLAYER * C3 * NC / 4);
  cvt_kernel<<<2048, 256, 0, stream>>>(proj_w, wb_proj, NLAYER * NC * NC / 4);
  cvt_kernel<<<2048, 256, 0, stream>>>(fc_w, wb_fc, NLAYER * C4 * NC / 4);
  cvt_kernel<<<2048, 256, 0, stream>>>(fc2_w, wb_fc2, NLAYER * NC * C4 / 4);

  embed_kernel<<<NB * NT, 256, 0, stream>>>(idx, wte, wpe, x);

  for (int l = 0; l < NLAYER; l++) {
    ln_kernel<<<512, 256, 0, stream>>>(x, ln1_w + (size_t)l * NC, ln1_b + (size_t)l * NC, h);
    gemm_kernel<128, 128, 0><<<dim3(C3 / 128, 16), 256, 0, stream>>>(
        h, wb_attn + (size_t)l * C3 * NC, attn_b + (size_t)l * C3, nullptr, qkv, vT, C3, NC);
    attn_kernel<<<512, 256, 0, stream>>>(qkv, vT, o);
    gemm_kernel<64, 64, 1><<<dim3(NC / 64, 32), 256, 0, stream>>>(
        o, wb_proj + (size_t)l * NC * NC, proj_b + (size_t)l * NC, x, nullptr, nullptr, NC, NC);
    ln_kernel<<<512, 256, 0, stream>>>(x, ln2_w + (size_t)l * NC, ln2_b + (size_t)l * NC, h);
    gemm_kernel<128, 128, 2><<<dim3(C4 / 128, 16), 256, 0, stream>>>(
        h, wb_fc + (size_t)l * C4 * NC, fc_b + (size_t)l * C4, nullptr, h2, nullptr, C4, NC);
    gemm_kernel<64, 64, 1><<<dim3(NC / 64, 32), 256, 0, stream>>>(
        h2, wb_fc2 + (size_t)l * NC * C4, fc2_b + (size_t)l * NC, x, nullptr, nullptr, NC, C4);
  }

  lmhead_kernel<<<512, 256, 0, stream>>>(x, lnf_w, lnf_b, wte, (float*)d_out);
}